// Round 7
// baseline (349.899 us; speedup 1.0000x reference)
//
#include <hip/hip_runtime.h>
#include <hip/hip_bf16.h>
#include <math.h>

// Problem constants
#define BB 4
#define SS 2048
#define DD 1024
#define HH 16
#define DHE 64
#define NH (HH*DHE)   // 1024
constexpr float NEG_BIG = -1e30f;     // exp2(NEG_BIG) == 0, never NaN
constexpr float K_PRESCALE = 0.18033688f;  // 0.125 * log2(e): folded into WkT

typedef __bf16 bf16x8 __attribute__((ext_vector_type(8)));
typedef float  f32x4  __attribute__((ext_vector_type(4)));

#define WAITVM6()   asm volatile("s_waitcnt vmcnt(6)" ::: "memory")
#define WAITVM4()   asm volatile("s_waitcnt vmcnt(4)" ::: "memory")
#define WAITVM0()   asm volatile("s_waitcnt vmcnt(0)" ::: "memory")
#define WAITLGKM0() asm volatile("s_waitcnt lgkmcnt(0)" ::: "memory")
#define MEMFENCE()  asm volatile("" ::: "memory")

// Async global->LDS 16B per lane: LDS dest is wave-uniform base + lane*16.
__device__ __forceinline__ void gl_lds16(const __bf16* g, __bf16* l) {
  __builtin_amdgcn_global_load_lds(
      (const __attribute__((address_space(1))) unsigned int*)g,
      (__attribute__((address_space(3))) unsigned int*)l, 16, 0, 0);
}

// Pack two fp32 -> one u32 of two bf16
__device__ __forceinline__ unsigned pack_bf2(float lo, float hi) {
  union { __bf16 h[2]; unsigned u; } p;
  p.h[0] = (__bf16)lo; p.h[1] = (__bf16)hi;
  return p.u;
}

// ---------------------------------------------------------------------------
// fp32 -> bf16 bulk convert (3 tensors, one launch).
// ---------------------------------------------------------------------------
__global__ __launch_bounds__(256) void cvt_k(
    const float* __restrict__ x0, const float* __restrict__ x1,
    const float* __restrict__ x2,
    __bf16* __restrict__ o0, __bf16* __restrict__ o1, __bf16* __restrict__ o2) {
  const float* x = blockIdx.z == 0 ? x0 : blockIdx.z == 1 ? x1 : x2;
  __bf16*      o = blockIdx.z == 0 ? o0 : blockIdx.z == 1 ? o1 : o2;
  const size_t n8 = (size_t)BB * SS * DD / 8;
  for (size_t i = (size_t)blockIdx.x * 256 + threadIdx.x; i < n8;
       i += (size_t)gridDim.x * 256) {
    f32x4 a = *(const f32x4*)(x + i * 8);
    f32x4 b = *(const f32x4*)(x + i * 8 + 4);
    bf16x8 v;
    #pragma unroll
    for (int j = 0; j < 4; j++) { v[j] = (__bf16)a[j]; v[j + 4] = (__bf16)b[j]; }
    *(bf16x8*)(o + i * 8) = v;
  }
}

// ---------------------------------------------------------------------------
// Transpose 4 weight matrices fp32 [k][n] -> bf16 WT[n][k].
// Wk (z==1) is pre-scaled by 0.125*log2e so attn's softmax is exp2(S) with
// NO per-score multiply (scale applied in f32 before the single bf16
// rounding -> same error profile as unscaled).
// ---------------------------------------------------------------------------
__global__ __launch_bounds__(256) void wtrans_k(
    const float* __restrict__ w0, const float* __restrict__ w1,
    const float* __restrict__ w2, const float* __restrict__ w3,
    __bf16* __restrict__ o0, __bf16* __restrict__ o1,
    __bf16* __restrict__ o2, __bf16* __restrict__ o3) {
  __shared__ __bf16 t[32][33];
  const float* w = blockIdx.z == 0 ? w0 : blockIdx.z == 1 ? w1 : blockIdx.z == 2 ? w2 : w3;
  __bf16*      o = blockIdx.z == 0 ? o0 : blockIdx.z == 1 ? o1 : blockIdx.z == 2 ? o2 : o3;
  const float sc = blockIdx.z == 1 ? K_PRESCALE : 1.0f;
  int tx = threadIdx.x & 31, ty = threadIdx.x >> 5;   // 32 x 8
  int bk = blockIdx.x * 32, bn = blockIdx.y * 32;
  #pragma unroll
  for (int i = 0; i < 4; i++)
    t[ty + i * 8][tx] = (__bf16)(w[(size_t)(bk + ty + i * 8) * DD + bn + tx] * sc);
  __syncthreads();
  #pragma unroll
  for (int i = 0; i < 4; i++)
    o[(size_t)(bn + ty + i * 8) * DD + bk + tx] = t[tx][ty + i * 8];
}

// ---------------------------------------------------------------------------
// Transpose V (bf16): v[s][col] -> o[col][s]  (fallback paths only)
// ---------------------------------------------------------------------------
__global__ __launch_bounds__(256) void vtrans_k(
    const __bf16* __restrict__ v, __bf16* __restrict__ o) {
  __shared__ __bf16 t[32][33];
  int tx = threadIdx.x & 31, ty = threadIdx.x >> 5;
  int bs = blockIdx.x * 32, bc = blockIdx.y * 32;
  const __bf16* vz = v + (size_t)blockIdx.z * SS * NH;
  __bf16*       oz = o + (size_t)blockIdx.z * NH * SS;
  #pragma unroll
  for (int i = 0; i < 4; i++)
    t[ty + i * 8][tx] = vz[(size_t)(bs + ty + i * 8) * NH + bc + tx];
  __syncthreads();
  #pragma unroll
  for (int i = 0; i < 4; i++)
    oz[(size_t)(bc + ty + i * 8) * SS + bs + tx] = t[tx][ty + i * 8];
}

// ---------------------------------------------------------------------------
// Batched-operand pack: z selects (A, BT, C).
// ---------------------------------------------------------------------------
struct B3 {
  const void*  a0; const void*  a1; const void*  a2;
  const __bf16* b0; const __bf16* b1; const __bf16* b2;
  void* c0; void* c1; void* c2;
};

// ---------------------------------------------------------------------------
// All-bf16 128x128 GEMM, single barrier/iter, ring-3 gl_lds staging (round 6)
// + ROUND 7: fused transposed epilogue for the V projection (z == vz):
// the C tile is staged into LDS (transposed write), then stored coalesced
// along s into VT[col][s]. Deletes the vtrans dispatch + 32 MB of Vb traffic.
// ---------------------------------------------------------------------------
template <typename CT>
__global__ __launch_bounds__(256, 3) void gemm_bb(B3 p, int vz) {
  __shared__ __align__(16) __bf16 smbuf[24576];   // 48 KB carve
  __bf16 (*Asr)[128][32] = (__bf16 (*)[128][32])smbuf;           // [3][128][32]
  __bf16 (*Bsr)[128][32] = (__bf16 (*)[128][32])(smbuf + 12288); // [3][128][32]
  __bf16 (*smT)[136]     = (__bf16 (*)[136])smbuf;               // [128][136]

  // XCD-chunked swizzle (nwg % 8 == 0 for all launches here).
  const unsigned nwg  = gridDim.x * gridDim.y * gridDim.z;
  const unsigned flat = blockIdx.x + gridDim.x * (blockIdx.y + gridDim.y * blockIdx.z);
  const unsigned swz  = (flat & 7) * (nwg >> 3) + (flat >> 3);
  const int bx = swz % gridDim.x;
  const unsigned rem = swz / gridDim.x;
  const int by = rem % gridDim.y;
  const int z  = rem / gridDim.y;

  const __bf16* __restrict__ A  = (const __bf16*)(z == 0 ? p.a0 : z == 1 ? p.a1 : p.a2);
  const __bf16* __restrict__ BT = z == 0 ? p.b0 : z == 1 ? p.b1 : p.b2;
  CT* __restrict__ C = (CT*)(z == 0 ? p.c0 : z == 1 ? p.c1 : p.c2);

  const int tid  = threadIdx.x;
  const int wave = tid >> 6, lane = tid & 63;
  const int quad = lane >> 4, l16 = lane & 15;
  const int wr = (wave >> 1) * 64, wc = (wave & 1) * 64;
  const int m0 = by * 128, n0 = bx * 128;

  f32x4 acc[4][4] = {};

  auto issue = [&](int it, int slot) {
    const int k0 = it * 32;
    const int rr  = lane >> 2;                     // 0..15
    const int seg = (lane & 3) ^ ((rr >> 1) & 3);  // logical seg at this phys slot
    #pragma unroll
    for (int i = 0; i < 2; i++) {
      const int row = wave * 16 + i * 64 + rr;
      gl_lds16(&A [(size_t)(m0 + row) * DD + k0 + seg * 8], &Asr[slot][wave * 16 + i * 64][0]);
      gl_lds16(&BT[(size_t)(n0 + row) * DD + k0 + seg * 8], &Bsr[slot][wave * 16 + i * 64][0]);
    }
  };

  auto compute = [&](int s) {
    bf16x8 af[4], bfr[4];
    const int ph = (quad ^ ((l16 >> 1) & 3)) * 8;
    #pragma unroll
    for (int t = 0; t < 4; t++) {
      af[t]  = *(const bf16x8*)&Asr[s][wr + t * 16 + l16][ph];
      bfr[t] = *(const bf16x8*)&Bsr[s][wc + t * 16 + l16][ph];
    }
    __builtin_amdgcn_s_setprio(1);
    #pragma unroll
    for (int mt = 0; mt < 4; mt++)
      #pragma unroll
      for (int nt = 0; nt < 4; nt++)
        acc[mt][nt] = __builtin_amdgcn_mfma_f32_16x16x32_bf16(af[mt], bfr[nt], acc[mt][nt], 0, 0, 0);
    __builtin_amdgcn_s_setprio(0);
  };

  issue(0, 0); MEMFENCE();
  issue(1, 1); MEMFENCE();

  int cur = 0, pre = 2;
  #pragma unroll 1
  for (int it = 0; it < 30; it++) {
    WAITVM4();
    __builtin_amdgcn_s_barrier();
    issue(it + 2, pre);
    compute(cur);
    cur = cur == 2 ? 0 : cur + 1;
    pre = pre == 2 ? 0 : pre + 1;
  }
  WAITVM4(); __builtin_amdgcn_s_barrier(); compute(cur);
  cur = cur == 2 ? 0 : cur + 1;
  WAITVM0(); __builtin_amdgcn_s_barrier(); compute(cur);

  if constexpr (sizeof(CT) == 2) {
    if (z == vz) {
      // Transposed epilogue: C tile -> VT[col][s] (coalesced along s).
      __syncthreads();                 // all waves done reading Asr/Bsr
      #pragma unroll
      for (int mt = 0; mt < 4; mt++)
        #pragma unroll
        for (int nt = 0; nt < 4; nt++)
          #pragma unroll
          for (int r = 0; r < 4; r++)
            smT[wc + nt * 16 + l16][wr + mt * 16 + quad * 4 + r] = (__bf16)acc[mt][nt][r];
      __syncthreads();
      const int b  = m0 >> 11;          // batch of this 128-row band
      const int s0 = m0 & 2047;
      __bf16* VTp = (__bf16*)C + (size_t)b * NH * SS;
      const int sseg = (tid & 15) * 8;
      #pragma unroll
      for (int g = 0; g < 8; g++) {
        const int cl = (tid >> 4) + g * 16;
        bf16x8 vv = *(const bf16x8*)&smT[cl][sseg];
        *(bf16x8*)&VTp[(size_t)(n0 + cl) * SS + s0 + sseg] = vv;
      }
      return;
    }
  }

  // Normal epilogue: C/D layout col=lane&15, row=quad*4+r
  #pragma unroll
  for (int mt = 0; mt < 4; mt++)
    #pragma unroll
    for (int nt = 0; nt < 4; nt++)
      #pragma unroll
      for (int r = 0; r < 4; r++) {
        int row = m0 + wr + mt * 16 + quad * 4 + r;
        int col = n0 + wc + nt * 16 + l16;
        C[(size_t)row * NH + col] = (CT)acc[mt][nt][r];
      }
}

// ---------------------------------------------------------------------------
// LEGACY fallback GEMM (round-5 structure). Small-workspace paths only.
// ---------------------------------------------------------------------------
template <typename AT> struct AStage;
template <> struct AStage<float>  { f32x4 d[2][2]; };
template <> struct AStage<__bf16> { bf16x8 d[2]; };

template <typename AT, typename CT>
__global__ __launch_bounds__(256, 3) void gemm_bt(B3 p, size_t aoff) {
  __shared__ __bf16 As[128][40];
  __shared__ __bf16 Bs[4][128][32];
  const unsigned nwg  = gridDim.x * gridDim.y * gridDim.z;
  const unsigned flat = blockIdx.x + gridDim.x * (blockIdx.y + gridDim.y * blockIdx.z);
  const unsigned swz  = (flat & 7) * (nwg >> 3) + (flat >> 3);
  const int bx = swz % gridDim.x;
  const unsigned rem = swz / gridDim.x;
  const int by = rem % gridDim.y;
  const int z  = rem / gridDim.y;

  const AT* __restrict__ A = (const AT*)(z == 0 ? p.a0 : z == 1 ? p.a1 : p.a2);
  const __bf16* __restrict__ BT = z == 0 ? p.b0 : z == 1 ? p.b1 : p.b2;
  CT* __restrict__ C = (CT*)(z == 0 ? p.c0 : z == 1 ? p.c1 : p.c2);

  const int tid  = threadIdx.x;
  const int wave = tid >> 6, lane = tid & 63;
  const int quad = lane >> 4, l16 = lane & 15;
  const int wr = (wave >> 1) * 64, wc = (wave & 1) * 64;
  const int m0 = by * 128, n0 = bx * 128;

  f32x4 acc[4][4] = {};
  AStage<AT> aA, aB;

  auto loadA = [&](int k0, AStage<AT>& S) {
    #pragma unroll
    for (int i = 0; i < 2; i++) {
      int c = tid + i * 256;
      int row = c >> 2, seg = (c & 3) * 8;
      if constexpr (sizeof(AT) == 4) {
        const float* ap = (const float*)A + aoff + (size_t)(m0 + row) * DD + k0 + seg;
        S.d[i][0] = *(const f32x4*)ap;
        S.d[i][1] = *(const f32x4*)(ap + 4);
      } else {
        S.d[i] = *(const bf16x8*)((const __bf16*)A + aoff + (size_t)(m0 + row) * DD + k0 + seg);
      }
    }
  };
  auto issueB = [&](int k0, int buf) {
    #pragma unroll
    for (int i = 0; i < 2; i++) {
      int rr  = lane >> 2;
      int row = wave * 16 + i * 64 + rr;
      int seg = (lane & 3) ^ ((rr >> 1) & 3);
      gl_lds16(&BT[(size_t)(n0 + row) * DD + k0 + seg * 8],
               &Bs[buf][wave * 16 + i * 64][0]);
    }
  };

  auto step = [&](int it, AStage<AT>& S, bool last, bool tail) {
    if (last) { WAITVM0(); }
    else if constexpr (sizeof(AT) == 4) { WAITVM6(); }
    else { WAITVM4(); }
    __builtin_amdgcn_s_barrier();
    #pragma unroll
    for (int i = 0; i < 2; i++) {
      int c = tid + i * 256;
      bf16x8 av;
      if constexpr (sizeof(AT) == 4) {
        #pragma unroll
        for (int j = 0; j < 4; j++) {
          av[j]     = (__bf16)S.d[i][0][j];
          av[j + 4] = (__bf16)S.d[i][1][j];
        }
      } else {
        av = S.d[i];
      }
      *(bf16x8*)&As[c >> 2][(c & 3) * 8] = av;
    }
    WAITLGKM0();
    __builtin_amdgcn_s_barrier();
    if (!tail) {
      issueB((it + 2) * 32, (it + 2) & 3);
      loadA((it + 2) * 32, S);
    }
    const int buf = it & 3;
    bf16x8 af[4], bfr[4];
    #pragma unroll
    for (int t = 0; t < 4; t++) {
      af[t]  = *(const bf16x8*)&As[wr + t * 16 + l16][quad * 8];
      bfr[t] = *(const bf16x8*)&Bs[buf][wc + t * 16 + l16][(quad ^ ((l16 >> 1) & 3)) * 8];
    }
    __builtin_amdgcn_s_setprio(1);
    #pragma unroll
    for (int mt = 0; mt < 4; mt++)
      #pragma unroll
      for (int nt = 0; nt < 4; nt++)
        acc[mt][nt] = __builtin_amdgcn_mfma_f32_16x16x32_bf16(af[mt], bfr[nt], acc[mt][nt], 0, 0, 0);
    __builtin_amdgcn_s_setprio(0);
  };

  issueB(0, 0);  loadA(0, aA);
  MEMFENCE();
  issueB(32, 1); loadA(32, aB);
  MEMFENCE();

  for (int it2 = 0; it2 < 15; it2++) {
    step(2 * it2,     aA, false, false);
    step(2 * it2 + 1, aB, false, false);
  }
  step(30, aA, false, true);
  step(31, aB, true,  true);

  #pragma unroll
  for (int mt = 0; mt < 4; mt++)
    #pragma unroll
    for (int nt = 0; nt < 4; nt++)
      #pragma unroll
      for (int r = 0; r < 4; r++) {
        int row = m0 + wr + mt * 16 + quad * 4 + r;
        int col = n0 + wc + nt * 16 + l16;
        C[(size_t)row * NH + col] = (CT)acc[mt][nt][r];
      }
}

// ---------------------------------------------------------------------------
// Causal flash attention, ROUND 7: 2-wave blocks (BQ=32), paired triangle.
//  - K pre-scaled by 0.125*log2e (wtrans) -> softmax is raw exp2(S): no
//    per-score multiply, no Q prescale pass.
//  - BQ 64->32 with 2 waves: same per-wave work but 2048 equal blocks =
//    8 blocks/CU resident (LDS 17.4KB x8 = 139KB), 8 independent barrier
//    domains -> VALU/MFMA/staging phases overlap across blocks.
//  - q-tiles of 32 (qt2 = 0..63), pairing (63-bx, bx): 33 tiles/block.
//  - XCD grouping: 32 consecutive slots on one XCD = one (h,z).
// ---------------------------------------------------------------------------
__global__ __launch_bounds__(128, 4) void attn_k(
    const __bf16* __restrict__ Q, const __bf16* __restrict__ K,
    const __bf16* __restrict__ VT, __bf16* __restrict__ O) {
  __shared__ __bf16 Ks[64][68];   // [kpos][dh]
  __shared__ __bf16 Vs[64][68];   // [dh][kpos]

  const int tid  = threadIdx.x;
  const int wave = tid >> 6, lane = tid & 63;   // wave in {0,1}
  const int quad = lane >> 4, l16 = lane & 15;

  // XCD-grouped decode: 32 consecutive slots on one XCD form one (h,z).
  const int n    = blockIdx.x;
  const int xcd  = n & 7, slot = n >> 3;
  const int gidx = xcd + 8 * (slot >> 5);   // (h,z) group id
  const int bx   = slot & 31;               // pair index 0..31
  const int h = gidx & 15, z = gidx >> 4;

  const __bf16* Qg = Q + (size_t)z * SS * NH + h * DHE;      // [s][dh] stride NH
  const __bf16* Kg = K + (size_t)z * SS * NH + h * DHE;
  const __bf16* Vg = VT + ((size_t)z * HH + h) * DHE * SS;   // [dh][s]
  __bf16*       Og = O + (size_t)z * SS * NH + h * DHE;

  bf16x8 kreg[4], vreg[4];
  auto loadKV = [&](int k0) {
    #pragma unroll
    for (int i = 0; i < 4; i++) {
      int v = tid + i * 128;   // 0..511 chunks of 8 elems = 64x64 tile
      kreg[i] = *(const bf16x8*)&Kg[(size_t)(k0 + (v >> 3)) * NH + (v & 7) * 8];
      vreg[i] = *(const bf16x8*)&Vg[(size_t)(v >> 3) * SS + k0 + (v & 7) * 8];
    }
  };

  #pragma unroll 1
  for (int seg = 0; seg < 2; seg++) {
    const int qt2 = seg ? bx : 63 - bx;      // {32..63} then {0..31}
    const int q0 = qt2 * 32;
    const int ntiles = qt2 / 2 + 1;          // 64-wide k-tiles incl. diagonal
    const int qpar = qt2 & 1;

    // Q frag raw (K carries the softmax scale). Lane l16 = q-col.
    const int qrow = q0 + wave * 16 + l16;
    bf16x8 qf[2];
    #pragma unroll
    for (int kk = 0; kk < 2; kk++)
      qf[kk] = *(const bf16x8*)&Qg[(size_t)qrow * NH + kk * 32 + quad * 8];

    loadKV(0);
    float prows = 0.f;
    f32x4 oacc[4] = {};

    for (int kt = 0; kt < ntiles; kt++) {
      const int k0 = kt * 64;
      __syncthreads();
      #pragma unroll
      for (int i = 0; i < 4; i++) {
        int v = tid + i * 128;
        *(bf16x8*)&Ks[v >> 3][(v & 7) * 8] = kreg[i];
        *(bf16x8*)&Vs[v >> 3][(v & 7) * 8] = vreg[i];
      }
      __syncthreads();
      if (kt + 1 < ntiles) loadKV(k0 + 64);

      const bool diag = (kt == ntiles - 1);
      // diag: wave w live 16-kpos blocks: even qt2 -> w+1, odd qt2 -> w+3.
      const int nq  = diag ? (qpar ? wave + 3 : wave + 1) : 4;
      const int nsm = (nq + 1) & ~1;           // even (zero-fill partner)
      const int nkk = nsm >> 1;                // PV 32-wide k-chunks

      // S^T = K_scaled Q^T : sc[nt] holds kpos rows nt*16+quad*4+r, q col l16
      f32x4 sc[4] = {};
      __builtin_amdgcn_s_setprio(1);
      #pragma unroll
      for (int kk = 0; kk < 2; kk++)
        #pragma unroll
        for (int nt = 0; nt < 4; nt++)
          if (nt < nq) {
            bf16x8 kf = *(const bf16x8*)&Ks[nt * 16 + l16][kk * 32 + quad * 8];
            sc[nt] = __builtin_amdgcn_mfma_f32_16x16x32_bf16(kf, qf[kk], sc[nt], 0, 0, 0);
          }
      __builtin_amdgcn_s_setprio(0);

      // Register softmax (p = exp2(s), scale folded into K) + P->A-frag
      // build via 4-lane stride-16 transpose.
      bf16x8 pf[2];
      #pragma unroll
      for (int t = 0; t < 2; t++)
        if (t < nkk) {
          const int nt0 = 2 * t, nt1 = 2 * t + 1;
          float pA[4], pB[4];
          #pragma unroll
          for (int r = 0; r < 4; r++) {
            float v0 = sc[nt0][r], v1 = sc[nt1][r];
            if (diag) {
              const int kb = k0 + quad * 4 + r;
              if (kb + nt0 * 16 > qrow) v0 = NEG_BIG;
              if (kb + nt1 * 16 > qrow) v1 = NEG_BIG;
            }
            pA[r] = __builtin_amdgcn_exp2f(v0);
            pB[r] = __builtin_amdgcn_exp2f(v1);
            prows += pA[r] + pB[r];
          }
          unsigned a0 = pack_bf2(pA[0], pA[1]), a1 = pack_bf2(pA[2], pA[3]);
          unsigned b0 = pack_bf2(pB[0], pB[1]), b1 = pack_bf2(pB[2], pB[3]);
          unsigned x0 = (quad & 1) ? a0 : b0, x1 = (quad & 1) ? a1 : b1;
          unsigned y0 = (quad & 1) ? b0 : a0, y1 = (quad & 1) ? b1 : a1;
          unsigned r16_0 = __shfl_xor((int)x0, 16), r16_1 = __shfl_xor((int)x1, 16);
          unsigned r32_0 = __shfl_xor((int)x0, 32), r32_1 = __shfl_xor((int)x1, 32);
          unsigned r48_0 = __shfl_xor((int)y0, 48), r48_1 = __shfl_xor((int)y1, 48);
          unsigned w0 = quad == 0 ? a0    : quad == 1 ? r48_0 : quad == 2 ? r32_0 : r16_0;
          unsigned w1 = quad == 0 ? a1    : quad == 1 ? r48_1 : quad == 2 ? r32_1 : r16_1;
          unsigned w2 = quad == 0 ? r16_0 : quad == 1 ? r32_0 : quad == 2 ? r48_0 : b0;
          unsigned w3 = quad == 0 ? r16_1 : quad == 1 ? r32_1 : quad == 2 ? r48_1 : b1;
          union { unsigned u[4]; bf16x8 v; } asm_;
          asm_.u[0] = w0; asm_.u[1] = w1; asm_.u[2] = w2; asm_.u[3] = w3;
          pf[t] = asm_.v;
        }

      // O += P V
      __builtin_amdgcn_s_setprio(1);
      #pragma unroll
      for (int kk = 0; kk < 2; kk++)
        if (kk < nkk) {
          #pragma unroll
          for (int dt = 0; dt < 4; dt++) {
            bf16x8 vf = *(const bf16x8*)&Vs[dt * 16 + l16][kk * 32 + quad * 8];
            oacc[dt] = __builtin_amdgcn_mfma_f32_16x16x32_bf16(pf[kk], vf, oacc[dt], 0, 0, 0);
          }
        }
      __builtin_amdgcn_s_setprio(0);
    }

    prows += __shfl_xor(prows, 16, 64);
    prows += __shfl_xor(prows, 32, 64);

    #pragma unroll
    for (int r = 0; r < 4; r++) {
      float tot = __shfl(prows, quad * 4 + r, 64);
      float inv = tot > 0.f ? 1.0f / tot : 0.f;
      int qg = q0 + wave * 16 + quad * 4 + r;
      #pragma unroll
      for (int dt = 0; dt < 4; dt++)
        Og[(size_t)qg * NH + dt * 16 + l16] = (__bf16)(oacc[dt][r] * inv);
    }
  }
}

// ---------------------------------------------------------------------------
extern "C" void kernel_launch(void* const* d_in, const int* in_sizes, int n_in,
                              void* d_out, int out_size, void* d_ws, size_t ws_size,
                              hipStream_t stream) {
  const float* x_q = (const float*)d_in[0];
  const float* x_k = (const float*)d_in[1];
  const float* x_v = (const float*)d_in[2];
  // d_in[3] = causal mask — statically known, unused
  const float* Wq = (const float*)d_in[4];
  const float* Wk = (const float*)d_in[5];
  const float* Wv = (const float*)d_in[6];
  const float* Wo = (const float*)d_in[7];
  float* out = (float*)d_out;

  const size_t WTE = (size_t)DD * NH;           // 1M elems per weight
  const size_t PB  = (size_t)SS * NH;           // per-batch elems (2M)
  const size_t FULLB = (size_t)BB * PB;         // 8M elems

  char* ws = (char*)d_ws;
  __bf16* WqT = (__bf16*)ws;
  __bf16* WkT = WqT + WTE;
  __bf16* WvT = WkT + WTE;
  __bf16* WoT = WvT + WTE;
  __bf16* buf0 = WoT + WTE;                     // after 8 MB of weights

  wtrans_k<<<dim3(32, 32, 4), 256, 0, stream>>>(Wq, Wk, Wv, Wo, WqT, WkT, WvT, WoT);

  const size_t needFast = 4 * WTE * 2 + 4 * FULLB * 2 + 3 * FULLB * 2;  // 120 MB
  const size_t needFull = 4 * WTE * 2 + 4 * FULLB * 2;                  // 72 MB
  if (ws_size >= needFast) {
    __bf16* Qb  = buf0;
    __bf16* Kb  = Qb + FULLB;
    __bf16* Vb  = Kb + FULLB;         // unused (V goes straight to VT); Ob lives here
    __bf16* VT  = Vb + FULLB;
    __bf16* xqb = VT + FULLB;
    __bf16* xkb = xqb + FULLB;
    __bf16* xvb = xkb + FULLB;
    __bf16* Ob  = Vb;
    cvt_k<<<dim3(1024, 1, 3), 256, 0, stream>>>(x_q, x_k, x_v, xqb, xkb, xvb);
    B3 qkv = { xqb, xkb, xvb, WqT, WkT, WvT, Qb, Kb, VT };
    gemm_bb<__bf16><<<dim3(8, 64, 3), 256, 0, stream>>>(qkv, 2);   // z==2 -> VT
    attn_k<<<dim3((SS / 64) * HH * BB), 128, 0, stream>>>(Qb, Kb, VT, Ob);
    B3 og = { Ob, Ob, Ob, WoT, WoT, WoT, out, out, out };
    gemm_bb<float><<<dim3(8, 64, 1), 256, 0, stream>>>(og, -1);
  } else if (ws_size >= needFull) {
    __bf16* Qb = buf0;
    __bf16* Kb = Qb + FULLB;
    __bf16* Vb = Kb + FULLB;
    __bf16* VT = Vb + FULLB;
    __bf16* Ob = Vb;                  // alias
    B3 qkv = { x_q, x_k, x_v, WqT, WkT, WvT, Qb, Kb, Vb };
    gemm_bt<float, __bf16><<<dim3(8, 64, 3), 256, 0, stream>>>(qkv, 0);
    vtrans_k<<<dim3(SS / 32, NH / 32, BB), 256, 0, stream>>>(Vb, VT);
    attn_k<<<dim3((SS / 64) * HH * BB), 128, 0, stream>>>(Qb, Kb, VT, Ob);
    B3 og = { Ob, Ob, Ob, WoT, WoT, WoT, out, out, out };
    gemm_bt<__bf16, float><<<dim3(8, 64, 1), 256, 0, stream>>>(og, 0);
  } else {
    __bf16* Qb = buf0;
    __bf16* Kb = Qb + PB;
    __bf16* Vb = Kb + PB;
    __bf16* VT = Vb + PB;
    __bf16* Ob = Vb;                  // alias
    for (int b = 0; b < BB; b++) {
      const size_t boff = (size_t)b * PB;
      B3 qkv = { x_q, x_k, x_v, WqT, WkT, WvT, Qb, Kb, Vb };
      gemm_bt<float, __bf16><<<dim3(8, 16, 3), 256, 0, stream>>>(qkv, boff);
      vtrans_k<<<dim3(SS / 32, NH / 32, 1), 256, 0, stream>>>(Vb, VT);
      attn_k<<<dim3((SS / 64) * HH), 128, 0, stream>>>(Qb, Kb, VT, Ob);
      B3 og = { Ob, Ob, Ob, WoT, WoT, WoT, out + boff, out + boff, out + boff };
      gemm_bt<__bf16, float><<<dim3(8, 16, 1), 256, 0, stream>>>(og, 0);
    }
  }
}

// Round 8
// 320.388 us; speedup vs baseline: 1.0921x; 1.0921x over previous
//
#include <hip/hip_runtime.h>
#include <hip/hip_bf16.h>
#include <math.h>

// Problem constants
#define BB 4
#define SS 2048
#define DD 1024
#define HH 16
#define DHE 64
#define NH (HH*DHE)   // 1024
constexpr float NEG_BIG = -1e30f;     // exp2(NEG_BIG) == 0, never NaN
constexpr float K_PRESCALE = 0.18033688f;  // 0.125 * log2(e): folded into WkT

typedef __bf16 bf16x8 __attribute__((ext_vector_type(8)));
typedef float  f32x4  __attribute__((ext_vector_type(4)));

#define WAITVM6()   asm volatile("s_waitcnt vmcnt(6)" ::: "memory")
#define WAITVM4()   asm volatile("s_waitcnt vmcnt(4)" ::: "memory")
#define WAITVM0()   asm volatile("s_waitcnt vmcnt(0)" ::: "memory")
#define WAITLGKM0() asm volatile("s_waitcnt lgkmcnt(0)" ::: "memory")
#define MEMFENCE()  asm volatile("" ::: "memory")

// Async global->LDS 16B per lane: LDS dest is wave-uniform base + lane*16.
__device__ __forceinline__ void gl_lds16(const __bf16* g, __bf16* l) {
  __builtin_amdgcn_global_load_lds(
      (const __attribute__((address_space(1))) unsigned int*)g,
      (__attribute__((address_space(3))) unsigned int*)l, 16, 0, 0);
}

// Pack two fp32 -> one u32 of two bf16
__device__ __forceinline__ unsigned pack_bf2(float lo, float hi) {
  union { __bf16 h[2]; unsigned u; } p;
  p.h[0] = (__bf16)lo; p.h[1] = (__bf16)hi;
  return p.u;
}

// ---------------------------------------------------------------------------
// fp32 -> bf16 bulk convert (3 tensors, one launch).
// ---------------------------------------------------------------------------
__global__ __launch_bounds__(256) void cvt_k(
    const float* __restrict__ x0, const float* __restrict__ x1,
    const float* __restrict__ x2,
    __bf16* __restrict__ o0, __bf16* __restrict__ o1, __bf16* __restrict__ o2) {
  const float* x = blockIdx.z == 0 ? x0 : blockIdx.z == 1 ? x1 : x2;
  __bf16*      o = blockIdx.z == 0 ? o0 : blockIdx.z == 1 ? o1 : o2;
  const size_t n8 = (size_t)BB * SS * DD / 8;
  for (size_t i = (size_t)blockIdx.x * 256 + threadIdx.x; i < n8;
       i += (size_t)gridDim.x * 256) {
    f32x4 a = *(const f32x4*)(x + i * 8);
    f32x4 b = *(const f32x4*)(x + i * 8 + 4);
    bf16x8 v;
    #pragma unroll
    for (int j = 0; j < 4; j++) { v[j] = (__bf16)a[j]; v[j + 4] = (__bf16)b[j]; }
    *(bf16x8*)(o + i * 8) = v;
  }
}

// ---------------------------------------------------------------------------
// Transpose 4 weight matrices fp32 [k][n] -> bf16 WT[n][k].
// Wk (z==1) pre-scaled by 0.125*log2e so attn softmax is raw exp2(S).
// ---------------------------------------------------------------------------
__global__ __launch_bounds__(256) void wtrans_k(
    const float* __restrict__ w0, const float* __restrict__ w1,
    const float* __restrict__ w2, const float* __restrict__ w3,
    __bf16* __restrict__ o0, __bf16* __restrict__ o1,
    __bf16* __restrict__ o2, __bf16* __restrict__ o3) {
  __shared__ __bf16 t[32][33];
  const float* w = blockIdx.z == 0 ? w0 : blockIdx.z == 1 ? w1 : blockIdx.z == 2 ? w2 : w3;
  __bf16*      o = blockIdx.z == 0 ? o0 : blockIdx.z == 1 ? o1 : blockIdx.z == 2 ? o2 : o3;
  const float sc = blockIdx.z == 1 ? K_PRESCALE : 1.0f;
  int tx = threadIdx.x & 31, ty = threadIdx.x >> 5;   // 32 x 8
  int bk = blockIdx.x * 32, bn = blockIdx.y * 32;
  #pragma unroll
  for (int i = 0; i < 4; i++)
    t[ty + i * 8][tx] = (__bf16)(w[(size_t)(bk + ty + i * 8) * DD + bn + tx] * sc);
  __syncthreads();
  #pragma unroll
  for (int i = 0; i < 4; i++)
    o[(size_t)(bn + ty + i * 8) * DD + bk + tx] = t[tx][ty + i * 8];
}

// ---------------------------------------------------------------------------
// Transpose V (bf16): v[s][col] -> o[col][s]  (fallback paths only)
// ---------------------------------------------------------------------------
__global__ __launch_bounds__(256) void vtrans_k(
    const __bf16* __restrict__ v, __bf16* __restrict__ o) {
  __shared__ __bf16 t[32][33];
  int tx = threadIdx.x & 31, ty = threadIdx.x >> 5;
  int bs = blockIdx.x * 32, bc = blockIdx.y * 32;
  const __bf16* vz = v + (size_t)blockIdx.z * SS * NH;
  __bf16*       oz = o + (size_t)blockIdx.z * NH * SS;
  #pragma unroll
  for (int i = 0; i < 4; i++)
    t[ty + i * 8][tx] = vz[(size_t)(bs + ty + i * 8) * NH + bc + tx];
  __syncthreads();
  #pragma unroll
  for (int i = 0; i < 4; i++)
    oz[(size_t)(bc + ty + i * 8) * SS + bs + tx] = t[tx][ty + i * 8];
}

// ---------------------------------------------------------------------------
// Batched-operand pack: z selects (A, BT, C).
// ---------------------------------------------------------------------------
struct B3 {
  const void*  a0; const void*  a1; const void*  a2;
  const __bf16* b0; const __bf16* b1; const __bf16* b2;
  void* c0; void* c1; void* c2;
};

// ---------------------------------------------------------------------------
// All-bf16 128x128 GEMM, single barrier/iter, ring-3 gl_lds staging
// + fused transposed epilogue for the V projection (z == vz):
// C tile staged into LDS (transposed write), stored coalesced along s into
// VT[col][s]. Deletes the vtrans dispatch + 32 MB of Vb round-trip.
// ---------------------------------------------------------------------------
template <typename CT>
__global__ __launch_bounds__(256, 3) void gemm_bb(B3 p, int vz) {
  __shared__ __align__(16) __bf16 smbuf[24576];   // 48 KB carve
  __bf16 (*Asr)[128][32] = (__bf16 (*)[128][32])smbuf;           // [3][128][32]
  __bf16 (*Bsr)[128][32] = (__bf16 (*)[128][32])(smbuf + 12288); // [3][128][32]
  __bf16 (*smT)[136]     = (__bf16 (*)[136])smbuf;               // [128][136]

  // XCD-chunked swizzle (nwg % 8 == 0 for all launches here).
  const unsigned nwg  = gridDim.x * gridDim.y * gridDim.z;
  const unsigned flat = blockIdx.x + gridDim.x * (blockIdx.y + gridDim.y * blockIdx.z);
  const unsigned swz  = (flat & 7) * (nwg >> 3) + (flat >> 3);
  const int bx = swz % gridDim.x;
  const unsigned rem = swz / gridDim.x;
  const int by = rem % gridDim.y;
  const int z  = rem / gridDim.y;

  const __bf16* __restrict__ A  = (const __bf16*)(z == 0 ? p.a0 : z == 1 ? p.a1 : p.a2);
  const __bf16* __restrict__ BT = z == 0 ? p.b0 : z == 1 ? p.b1 : p.b2;
  CT* __restrict__ C = (CT*)(z == 0 ? p.c0 : z == 1 ? p.c1 : p.c2);

  const int tid  = threadIdx.x;
  const int wave = tid >> 6, lane = tid & 63;
  const int quad = lane >> 4, l16 = lane & 15;
  const int wr = (wave >> 1) * 64, wc = (wave & 1) * 64;
  const int m0 = by * 128, n0 = bx * 128;

  f32x4 acc[4][4] = {};

  auto issue = [&](int it, int slot) {
    const int k0 = it * 32;
    const int rr  = lane >> 2;                     // 0..15
    const int seg = (lane & 3) ^ ((rr >> 1) & 3);  // logical seg at this phys slot
    #pragma unroll
    for (int i = 0; i < 2; i++) {
      const int row = wave * 16 + i * 64 + rr;
      gl_lds16(&A [(size_t)(m0 + row) * DD + k0 + seg * 8], &Asr[slot][wave * 16 + i * 64][0]);
      gl_lds16(&BT[(size_t)(n0 + row) * DD + k0 + seg * 8], &Bsr[slot][wave * 16 + i * 64][0]);
    }
  };

  auto compute = [&](int s) {
    bf16x8 af[4], bfr[4];
    const int ph = (quad ^ ((l16 >> 1) & 3)) * 8;
    #pragma unroll
    for (int t = 0; t < 4; t++) {
      af[t]  = *(const bf16x8*)&Asr[s][wr + t * 16 + l16][ph];
      bfr[t] = *(const bf16x8*)&Bsr[s][wc + t * 16 + l16][ph];
    }
    __builtin_amdgcn_s_setprio(1);
    #pragma unroll
    for (int mt = 0; mt < 4; mt++)
      #pragma unroll
      for (int nt = 0; nt < 4; nt++)
        acc[mt][nt] = __builtin_amdgcn_mfma_f32_16x16x32_bf16(af[mt], bfr[nt], acc[mt][nt], 0, 0, 0);
    __builtin_amdgcn_s_setprio(0);
  };

  issue(0, 0); MEMFENCE();
  issue(1, 1); MEMFENCE();

  int cur = 0, pre = 2;
  #pragma unroll 1
  for (int it = 0; it < 30; it++) {
    WAITVM4();
    __builtin_amdgcn_s_barrier();
    issue(it + 2, pre);
    compute(cur);
    cur = cur == 2 ? 0 : cur + 1;
    pre = pre == 2 ? 0 : pre + 1;
  }
  WAITVM4(); __builtin_amdgcn_s_barrier(); compute(cur);
  cur = cur == 2 ? 0 : cur + 1;
  WAITVM0(); __builtin_amdgcn_s_barrier(); compute(cur);

  if constexpr (sizeof(CT) == 2) {
    if (z == vz) {
      // Transposed epilogue: C tile -> VT[col][s] (coalesced along s).
      __syncthreads();                 // all waves done reading Asr/Bsr
      #pragma unroll
      for (int mt = 0; mt < 4; mt++)
        #pragma unroll
        for (int nt = 0; nt < 4; nt++)
          #pragma unroll
          for (int r = 0; r < 4; r++)
            smT[wc + nt * 16 + l16][wr + mt * 16 + quad * 4 + r] = (__bf16)acc[mt][nt][r];
      __syncthreads();
      const int b  = m0 >> 11;          // batch of this 128-row band
      const int s0 = m0 & 2047;
      __bf16* VTp = (__bf16*)C + (size_t)b * NH * SS;
      const int sseg = (tid & 15) * 8;
      #pragma unroll
      for (int g = 0; g < 8; g++) {
        const int cl = (tid >> 4) + g * 16;
        bf16x8 vv = *(const bf16x8*)&smT[cl][sseg];
        *(bf16x8*)&VTp[(size_t)(n0 + cl) * SS + s0 + sseg] = vv;
      }
      return;
    }
  }

  // Normal epilogue: C/D layout col=lane&15, row=quad*4+r
  #pragma unroll
  for (int mt = 0; mt < 4; mt++)
    #pragma unroll
    for (int nt = 0; nt < 4; nt++)
      #pragma unroll
      for (int r = 0; r < 4; r++) {
        int row = m0 + wr + mt * 16 + quad * 4 + r;
        int col = n0 + wc + nt * 16 + l16;
        C[(size_t)row * NH + col] = (CT)acc[mt][nt][r];
      }
}

// ---------------------------------------------------------------------------
// LEGACY fallback GEMM (round-5 structure). Small-workspace paths only.
// ---------------------------------------------------------------------------
template <typename AT> struct AStage;
template <> struct AStage<float>  { f32x4 d[2][2]; };
template <> struct AStage<__bf16> { bf16x8 d[2]; };

template <typename AT, typename CT>
__global__ __launch_bounds__(256, 3) void gemm_bt(B3 p, size_t aoff) {
  __shared__ __bf16 As[128][40];
  __shared__ __bf16 Bs[4][128][32];
  const unsigned nwg  = gridDim.x * gridDim.y * gridDim.z;
  const unsigned flat = blockIdx.x + gridDim.x * (blockIdx.y + gridDim.y * blockIdx.z);
  const unsigned swz  = (flat & 7) * (nwg >> 3) + (flat >> 3);
  const int bx = swz % gridDim.x;
  const unsigned rem = swz / gridDim.x;
  const int by = rem % gridDim.y;
  const int z  = rem / gridDim.y;

  const AT* __restrict__ A = (const AT*)(z == 0 ? p.a0 : z == 1 ? p.a1 : p.a2);
  const __bf16* __restrict__ BT = z == 0 ? p.b0 : z == 1 ? p.b1 : p.b2;
  CT* __restrict__ C = (CT*)(z == 0 ? p.c0 : z == 1 ? p.c1 : p.c2);

  const int tid  = threadIdx.x;
  const int wave = tid >> 6, lane = tid & 63;
  const int quad = lane >> 4, l16 = lane & 15;
  const int wr = (wave >> 1) * 64, wc = (wave & 1) * 64;
  const int m0 = by * 128, n0 = bx * 128;

  f32x4 acc[4][4] = {};
  AStage<AT> aA, aB;

  auto loadA = [&](int k0, AStage<AT>& S) {
    #pragma unroll
    for (int i = 0; i < 2; i++) {
      int c = tid + i * 256;
      int row = c >> 2, seg = (c & 3) * 8;
      if constexpr (sizeof(AT) == 4) {
        const float* ap = (const float*)A + aoff + (size_t)(m0 + row) * DD + k0 + seg;
        S.d[i][0] = *(const f32x4*)ap;
        S.d[i][1] = *(const f32x4*)(ap + 4);
      } else {
        S.d[i] = *(const bf16x8*)((const __bf16*)A + aoff + (size_t)(m0 + row) * DD + k0 + seg);
      }
    }
  };
  auto issueB = [&](int k0, int buf) {
    #pragma unroll
    for (int i = 0; i < 2; i++) {
      int rr  = lane >> 2;
      int row = wave * 16 + i * 64 + rr;
      int seg = (lane & 3) ^ ((rr >> 1) & 3);
      gl_lds16(&BT[(size_t)(n0 + row) * DD + k0 + seg * 8],
               &Bs[buf][wave * 16 + i * 64][0]);
    }
  };

  auto step = [&](int it, AStage<AT>& S, bool last, bool tail) {
    if (last) { WAITVM0(); }
    else if constexpr (sizeof(AT) == 4) { WAITVM6(); }
    else { WAITVM4(); }
    __builtin_amdgcn_s_barrier();
    #pragma unroll
    for (int i = 0; i < 2; i++) {
      int c = tid + i * 256;
      bf16x8 av;
      if constexpr (sizeof(AT) == 4) {
        #pragma unroll
        for (int j = 0; j < 4; j++) {
          av[j]     = (__bf16)S.d[i][0][j];
          av[j + 4] = (__bf16)S.d[i][1][j];
        }
      } else {
        av = S.d[i];
      }
      *(bf16x8*)&As[c >> 2][(c & 3) * 8] = av;
    }
    WAITLGKM0();
    __builtin_amdgcn_s_barrier();
    if (!tail) {
      issueB((it + 2) * 32, (it + 2) & 3);
      loadA((it + 2) * 32, S);
    }
    const int buf = it & 3;
    bf16x8 af[4], bfr[4];
    #pragma unroll
    for (int t = 0; t < 4; t++) {
      af[t]  = *(const bf16x8*)&As[wr + t * 16 + l16][quad * 8];
      bfr[t] = *(const bf16x8*)&Bs[buf][wc + t * 16 + l16][(quad ^ ((l16 >> 1) & 3)) * 8];
    }
    __builtin_amdgcn_s_setprio(1);
    #pragma unroll
    for (int mt = 0; mt < 4; mt++)
      #pragma unroll
      for (int nt = 0; nt < 4; nt++)
        acc[mt][nt] = __builtin_amdgcn_mfma_f32_16x16x32_bf16(af[mt], bfr[nt], acc[mt][nt], 0, 0, 0);
    __builtin_amdgcn_s_setprio(0);
  };

  issueB(0, 0);  loadA(0, aA);
  MEMFENCE();
  issueB(32, 1); loadA(32, aB);
  MEMFENCE();

  for (int it2 = 0; it2 < 15; it2++) {
    step(2 * it2,     aA, false, false);
    step(2 * it2 + 1, aB, false, false);
  }
  step(30, aA, false, true);
  step(31, aB, true,  true);

  #pragma unroll
  for (int mt = 0; mt < 4; mt++)
    #pragma unroll
    for (int nt = 0; nt < 4; nt++)
      #pragma unroll
      for (int r = 0; r < 4; r++) {
        int row = m0 + wr + mt * 16 + quad * 4 + r;
        int col = n0 + wc + nt * 16 + l16;
        C[(size_t)row * NH + col] = (CT)acc[mt][nt][r];
      }
}

// ---------------------------------------------------------------------------
// Causal flash attention, ROUND 8 = round-6 geometry + exp2 softmax.
// BQ=64, 4 waves, 1024 equal-work blocks (paired triangle: 33 tiles each),
// XCD grouping, swapped QK^T, register softmax.
// K pre-scaled by 0.125*log2e (wtrans) -> p = exp2(s) directly: no Q
// prescale pass, no per-score multiply.
// (Round 7's BQ=32 halved rows/block with the same K/V tiles -> 2x staging
// traffic per FLOP, FETCH 28->73 MB, partial-line O writes 16->61 MB; the
// memory system became the limiter. Reverted.)
// ---------------------------------------------------------------------------
__global__ __launch_bounds__(256, 4) void attn_k(
    const __bf16* __restrict__ Q, const __bf16* __restrict__ K,
    const __bf16* __restrict__ VT, __bf16* __restrict__ O) {
  __shared__ __bf16 Ks[64][68];   // [kpos][dh]
  __shared__ __bf16 Vs[64][68];   // [dh][kpos]

  const int tid  = threadIdx.x;
  const int wave = tid >> 6, lane = tid & 63;
  const int quad = lane >> 4, l16 = lane & 15;

  // XCD-grouped decode: 16 consecutive slots on one XCD form one (h,z).
  const int n    = blockIdx.x;
  const int xcd  = n & 7, slot = n >> 3;
  const int gidx = xcd + 8 * (slot >> 4);   // (h,z) group id
  const int bx   = slot & 15;               // pair index 0..15
  const int h = gidx & 15, z = gidx >> 4;

  const __bf16* Qg = Q + (size_t)z * SS * NH + h * DHE;      // [s][dh] stride NH
  const __bf16* Kg = K + (size_t)z * SS * NH + h * DHE;
  const __bf16* Vg = VT + ((size_t)z * HH + h) * DHE * SS;   // [dh][s]
  __bf16*       Og = O + (size_t)z * SS * NH + h * DHE;

  bf16x8 kreg[2], vreg[2];
  auto loadKV = [&](int k0) {
    #pragma unroll
    for (int i = 0; i < 2; i++) {
      int v = tid + i * 256;   // 0..511 chunks of 8 elems = 64x64 tile
      kreg[i] = *(const bf16x8*)&Kg[(size_t)(k0 + (v >> 3)) * NH + (v & 7) * 8];
      vreg[i] = *(const bf16x8*)&Vg[(size_t)(v >> 3) * SS + k0 + (v & 7) * 8];
    }
  };

  #pragma unroll 1
  for (int seg = 0; seg < 2; seg++) {
    const int qt = seg ? bx : 31 - bx;       // {16..31} then {0..15}
    const int q0 = qt * 64;
    const int ntiles = qt + 1;

    // Q frag raw (K carries the softmax scale). Lane l16 = q-col.
    const int qrow = q0 + wave * 16 + l16;
    bf16x8 qf[2];
    #pragma unroll
    for (int kk = 0; kk < 2; kk++)
      qf[kk] = *(const bf16x8*)&Qg[(size_t)qrow * NH + kk * 32 + quad * 8];

    loadKV(0);
    float prows = 0.f;
    f32x4 oacc[4] = {};

    for (int kt = 0; kt < ntiles; kt++) {
      const int k0 = kt * 64;
      __syncthreads();
      #pragma unroll
      for (int i = 0; i < 2; i++) {
        int v = tid + i * 256;
        *(bf16x8*)&Ks[v >> 3][(v & 7) * 8] = kreg[i];
        *(bf16x8*)&Vs[v >> 3][(v & 7) * 8] = vreg[i];
      }
      __syncthreads();
      if (kt + 1 < ntiles) loadKV(k0 + 64);

      const bool diag = (kt == ntiles - 1);
      const int nq  = diag ? wave + 1 : 4;          // QK blocks with live data
      const int nsm = diag ? ((wave + 2) & ~1) : 4; // processed blocks (even)
      const int nkk = nsm >> 1;                     // PV 32-wide k-chunks

      // S^T = K_scaled Q^T : sc[nt] holds kpos rows nt*16+quad*4+r, q col l16
      f32x4 sc[4] = {};
      __builtin_amdgcn_s_setprio(1);
      #pragma unroll
      for (int kk = 0; kk < 2; kk++)
        #pragma unroll
        for (int nt = 0; nt < 4; nt++)
          if (nt < nq) {
            bf16x8 kf = *(const bf16x8*)&Ks[nt * 16 + l16][kk * 32 + quad * 8];
            sc[nt] = __builtin_amdgcn_mfma_f32_16x16x32_bf16(kf, qf[kk], sc[nt], 0, 0, 0);
          }
      __builtin_amdgcn_s_setprio(0);

      // Register softmax (p = exp2(s)) + P->A-frag build via 4-lane
      // stride-16 transpose.
      bf16x8 pf[2];
      #pragma unroll
      for (int t = 0; t < 2; t++)
        if (t < nkk) {
          const int nt0 = 2 * t, nt1 = 2 * t + 1;
          float pA[4], pB[4];
          #pragma unroll
          for (int r = 0; r < 4; r++) {
            float v0 = sc[nt0][r], v1 = sc[nt1][r];
            if (diag) {
              const int kb = k0 + quad * 4 + r;
              if (kb + nt0 * 16 > qrow) v0 = NEG_BIG;
              if (kb + nt1 * 16 > qrow) v1 = NEG_BIG;
            }
            pA[r] = __builtin_amdgcn_exp2f(v0);
            pB[r] = __builtin_amdgcn_exp2f(v1);
            prows += pA[r] + pB[r];
          }
          unsigned a0 = pack_bf2(pA[0], pA[1]), a1 = pack_bf2(pA[2], pA[3]);
          unsigned b0 = pack_bf2(pB[0], pB[1]), b1 = pack_bf2(pB[2], pB[3]);
          unsigned x0 = (quad & 1) ? a0 : b0, x1 = (quad & 1) ? a1 : b1;
          unsigned y0 = (quad & 1) ? b0 : a0, y1 = (quad & 1) ? b1 : a1;
          unsigned r16_0 = __shfl_xor((int)x0, 16), r16_1 = __shfl_xor((int)x1, 16);
          unsigned r32_0 = __shfl_xor((int)x0, 32), r32_1 = __shfl_xor((int)x1, 32);
          unsigned r48_0 = __shfl_xor((int)y0, 48), r48_1 = __shfl_xor((int)y1, 48);
          unsigned w0 = quad == 0 ? a0    : quad == 1 ? r48_0 : quad == 2 ? r32_0 : r16_0;
          unsigned w1 = quad == 0 ? a1    : quad == 1 ? r48_1 : quad == 2 ? r32_1 : r16_1;
          unsigned w2 = quad == 0 ? r16_0 : quad == 1 ? r32_0 : quad == 2 ? r48_0 : b0;
          unsigned w3 = quad == 0 ? r16_1 : quad == 1 ? r32_1 : quad == 2 ? r48_1 : b1;
          union { unsigned u[4]; bf16x8 v; } asm_;
          asm_.u[0] = w0; asm_.u[1] = w1; asm_.u[2] = w2; asm_.u[3] = w3;
          pf[t] = asm_.v;
        }

      // O += P V
      __builtin_amdgcn_s_setprio(1);
      #pragma unroll
      for (int kk = 0; kk < 2; kk++)
        if (kk < nkk) {
          #pragma unroll
          for (int dt = 0; dt < 4; dt++) {
            bf16x8 vf = *(const bf16x8*)&Vs[dt * 16 + l16][kk * 32 + quad * 8];
            oacc[dt] = __builtin_amdgcn_mfma_f32_16x16x32_bf16(pf[kk], vf, oacc[dt], 0, 0, 0);
          }
        }
      __builtin_amdgcn_s_setprio(0);
    }

    prows += __shfl_xor(prows, 16, 64);
    prows += __shfl_xor(prows, 32, 64);

    #pragma unroll
    for (int r = 0; r < 4; r++) {
      float tot = __shfl(prows, quad * 4 + r, 64);
      float inv = tot > 0.f ? 1.0f / tot : 0.f;
      int qg = q0 + wave * 16 + quad * 4 + r;
      #pragma unroll
      for (int dt = 0; dt < 4; dt++)
        Og[(size_t)qg * NH + dt * 16 + l16] = (__bf16)(oacc[dt][r] * inv);
    }
  }
}

// ---------------------------------------------------------------------------
extern "C" void kernel_launch(void* const* d_in, const int* in_sizes, int n_in,
                              void* d_out, int out_size, void* d_ws, size_t ws_size,
                              hipStream_t stream) {
  const float* x_q = (const float*)d_in[0];
  const float* x_k = (const float*)d_in[1];
  const float* x_v = (const float*)d_in[2];
  // d_in[3] = causal mask — statically known, unused
  const float* Wq = (const float*)d_in[4];
  const float* Wk = (const float*)d_in[5];
  const float* Wv = (const float*)d_in[6];
  const float* Wo = (const float*)d_in[7];
  float* out = (float*)d_out;

  const size_t WTE = (size_t)DD * NH;           // 1M elems per weight
  const size_t PB  = (size_t)SS * NH;           // per-batch elems (2M)
  const size_t FULLB = (size_t)BB * PB;         // 8M elems

  char* ws = (char*)d_ws;
  __bf16* WqT = (__bf16*)ws;
  __bf16* WkT = WqT + WTE;
  __bf16* WvT = WkT + WTE;
  __bf16* WoT = WvT + WTE;
  __bf16* buf0 = WoT + WTE;                     // after 8 MB of weights

  wtrans_k<<<dim3(32, 32, 4), 256, 0, stream>>>(Wq, Wk, Wv, Wo, WqT, WkT, WvT, WoT);

  const size_t needFast = 4 * WTE * 2 + 4 * FULLB * 2 + 3 * FULLB * 2;  // 120 MB
  const size_t needFull = 4 * WTE * 2 + 4 * FULLB * 2;                  // 72 MB
  if (ws_size >= needFast) {
    __bf16* Qb  = buf0;
    __bf16* Kb  = Qb + FULLB;
    __bf16* Vb  = Kb + FULLB;         // Ob lives here (V goes straight to VT)
    __bf16* VT  = Vb + FULLB;
    __bf16* xqb = VT + FULLB;
    __bf16* xkb = xqb + FULLB;
    __bf16* xvb = xkb + FULLB;
    __bf16* Ob  = Vb;
    cvt_k<<<dim3(1024, 1, 3), 256, 0, stream>>>(x_q, x_k, x_v, xqb, xkb, xvb);
    B3 qkv = { xqb, xkb, xvb, WqT, WkT, WvT, Qb, Kb, VT };
    gemm_bb<__bf16><<<dim3(8, 64, 3), 256, 0, stream>>>(qkv, 2);   // z==2 -> VT
    attn_k<<<dim3((SS / 128) * HH * BB), 256, 0, stream>>>(Qb, Kb, VT, Ob);
    B3 og = { Ob, Ob, Ob, WoT, WoT, WoT, out, out, out };
    gemm_bb<float><<<dim3(8, 64, 1), 256, 0, stream>>>(og, -1);
  } else if (ws_size >= needFull) {
    __bf16* Qb = buf0;
    __bf16* Kb = Qb + FULLB;
    __bf16* Vb = Kb + FULLB;
    __bf16* VT = Vb + FULLB;
    __bf16* Ob = Vb;                  // alias
    B3 qkv = { x_q, x_k, x_v, WqT, WkT, WvT, Qb, Kb, Vb };
    gemm_bt<float, __bf16><<<dim3(8, 64, 3), 256, 0, stream>>>(qkv, 0);
    vtrans_k<<<dim3(SS / 32, NH / 32, BB), 256, 0, stream>>>(Vb, VT);
    attn_k<<<dim3((SS / 128) * HH * BB), 256, 0, stream>>>(Qb, Kb, VT, Ob);
    B3 og = { Ob, Ob, Ob, WoT, WoT, WoT, out, out, out };
    gemm_bt<__bf16, float><<<dim3(8, 64, 1), 256, 0, stream>>>(og, 0);
  } else {
    __bf16* Qb = buf0;
    __bf16* Kb = Qb + PB;
    __bf16* Vb = Kb + PB;
    __bf16* VT = Vb + PB;
    __bf16* Ob = Vb;                  // alias
    for (int b = 0; b < BB; b++) {
      const size_t boff = (size_t)b * PB;
      B3 qkv = { x_q, x_k, x_v, WqT, WkT, WvT, Qb, Kb, Vb };
      gemm_bt<float, __bf16><<<dim3(8, 16, 3), 256, 0, stream>>>(qkv, boff);
      vtrans_k<<<dim3(SS / 32, NH / 32, 1), 256, 0, stream>>>(Vb, VT);
      attn_k<<<dim3((SS / 128) * HH), 256, 0, stream>>>(Qb, Kb, VT, Ob);
      B3 og = { Ob, Ob, Ob, WoT, WoT, WoT, out + boff, out + boff, out + boff };
      gemm_bt<__bf16, float><<<dim3(8, 16, 1), 256, 0, stream>>>(og, 0);
    }
  }
}

// Round 9
// 307.585 us; speedup vs baseline: 1.1376x; 1.0416x over previous
//
#include <hip/hip_runtime.h>
#include <hip/hip_bf16.h>
#include <math.h>

// Problem constants
#define BB 4
#define SS 2048
#define DD 1024
#define HH 16
#define DHE 64
#define NH (HH*DHE)   // 1024
constexpr float NEG_BIG = -1e30f;     // exp2(NEG_BIG) == 0, never NaN
constexpr float K_PRESCALE = 0.18033688f;  // 0.125 * log2(e): folded into WkT

typedef __bf16 bf16x8 __attribute__((ext_vector_type(8)));
typedef float  f32x4  __attribute__((ext_vector_type(4)));

#define WAITVM6()   asm volatile("s_waitcnt vmcnt(6)" ::: "memory")
#define WAITVM4()   asm volatile("s_waitcnt vmcnt(4)" ::: "memory")
#define WAITVM0()   asm volatile("s_waitcnt vmcnt(0)" ::: "memory")
#define WAITLGKM0() asm volatile("s_waitcnt lgkmcnt(0)" ::: "memory")
#define MEMFENCE()  asm volatile("" ::: "memory")

// Async global->LDS 16B per lane: LDS dest is wave-uniform base + lane*16.
__device__ __forceinline__ void gl_lds16(const __bf16* g, __bf16* l) {
  __builtin_amdgcn_global_load_lds(
      (const __attribute__((address_space(1))) unsigned int*)g,
      (__attribute__((address_space(3))) unsigned int*)l, 16, 0, 0);
}

// Pack two fp32 -> one u32 of two bf16
__device__ __forceinline__ unsigned pack_bf2(float lo, float hi) {
  union { __bf16 h[2]; unsigned u; } p;
  p.h[0] = (__bf16)lo; p.h[1] = (__bf16)hi;
  return p.u;
}

// ---------------------------------------------------------------------------
// fp32 -> bf16 bulk convert (3 tensors, one launch).
// ---------------------------------------------------------------------------
__global__ __launch_bounds__(256) void cvt_k(
    const float* __restrict__ x0, const float* __restrict__ x1,
    const float* __restrict__ x2,
    __bf16* __restrict__ o0, __bf16* __restrict__ o1, __bf16* __restrict__ o2) {
  const float* x = blockIdx.z == 0 ? x0 : blockIdx.z == 1 ? x1 : x2;
  __bf16*      o = blockIdx.z == 0 ? o0 : blockIdx.z == 1 ? o1 : o2;
  const size_t n8 = (size_t)BB * SS * DD / 8;
  for (size_t i = (size_t)blockIdx.x * 256 + threadIdx.x; i < n8;
       i += (size_t)gridDim.x * 256) {
    f32x4 a = *(const f32x4*)(x + i * 8);
    f32x4 b = *(const f32x4*)(x + i * 8 + 4);
    bf16x8 v;
    #pragma unroll
    for (int j = 0; j < 4; j++) { v[j] = (__bf16)a[j]; v[j + 4] = (__bf16)b[j]; }
    *(bf16x8*)(o + i * 8) = v;
  }
}

// ---------------------------------------------------------------------------
// Transpose 4 weight matrices fp32 [k][n] -> bf16 WT[n][k].
// Wk (z==1) pre-scaled by 0.125*log2e so attn softmax is raw exp2(S).
// ---------------------------------------------------------------------------
__global__ __launch_bounds__(256) void wtrans_k(
    const float* __restrict__ w0, const float* __restrict__ w1,
    const float* __restrict__ w2, const float* __restrict__ w3,
    __bf16* __restrict__ o0, __bf16* __restrict__ o1,
    __bf16* __restrict__ o2, __bf16* __restrict__ o3) {
  __shared__ __bf16 t[32][33];
  const float* w = blockIdx.z == 0 ? w0 : blockIdx.z == 1 ? w1 : blockIdx.z == 2 ? w2 : w3;
  __bf16*      o = blockIdx.z == 0 ? o0 : blockIdx.z == 1 ? o1 : blockIdx.z == 2 ? o2 : o3;
  const float sc = blockIdx.z == 1 ? K_PRESCALE : 1.0f;
  int tx = threadIdx.x & 31, ty = threadIdx.x >> 5;   // 32 x 8
  int bk = blockIdx.x * 32, bn = blockIdx.y * 32;
  #pragma unroll
  for (int i = 0; i < 4; i++)
    t[ty + i * 8][tx] = (__bf16)(w[(size_t)(bk + ty + i * 8) * DD + bn + tx] * sc);
  __syncthreads();
  #pragma unroll
  for (int i = 0; i < 4; i++)
    o[(size_t)(bn + ty + i * 8) * DD + bk + tx] = t[tx][ty + i * 8];
}

// ---------------------------------------------------------------------------
// Transpose V (bf16): v[s][col] -> o[col][s]  (fallback paths only)
// ---------------------------------------------------------------------------
__global__ __launch_bounds__(256) void vtrans_k(
    const __bf16* __restrict__ v, __bf16* __restrict__ o) {
  __shared__ __bf16 t[32][33];
  int tx = threadIdx.x & 31, ty = threadIdx.x >> 5;
  int bs = blockIdx.x * 32, bc = blockIdx.y * 32;
  const __bf16* vz = v + (size_t)blockIdx.z * SS * NH;
  __bf16*       oz = o + (size_t)blockIdx.z * NH * SS;
  #pragma unroll
  for (int i = 0; i < 4; i++)
    t[ty + i * 8][tx] = vz[(size_t)(bs + ty + i * 8) * NH + bc + tx];
  __syncthreads();
  #pragma unroll
  for (int i = 0; i < 4; i++)
    oz[(size_t)(bc + ty + i * 8) * SS + bs + tx] = t[tx][ty + i * 8];
}

// ---------------------------------------------------------------------------
// Batched-operand pack: z selects (A, BT, C).
// ---------------------------------------------------------------------------
struct B3 {
  const void*  a0; const void*  a1; const void*  a2;
  const __bf16* b0; const __bf16* b1; const __bf16* b2;
  void* c0; void* c1; void* c2;
};

// ---------------------------------------------------------------------------
// All-bf16 128x128 GEMM, single barrier/iter, ring-3 gl_lds staging
// + fused transposed epilogue for the V projection (z == vz):
// C tile staged into LDS (transposed write), stored coalesced along s into
// VT[col][s]. Deletes the vtrans dispatch + 32 MB of Vb round-trip.
// ---------------------------------------------------------------------------
template <typename CT>
__global__ __launch_bounds__(256, 3) void gemm_bb(B3 p, int vz) {
  __shared__ __align__(16) __bf16 smbuf[24576];   // 48 KB carve
  __bf16 (*Asr)[128][32] = (__bf16 (*)[128][32])smbuf;           // [3][128][32]
  __bf16 (*Bsr)[128][32] = (__bf16 (*)[128][32])(smbuf + 12288); // [3][128][32]
  __bf16 (*smT)[136]     = (__bf16 (*)[136])smbuf;               // [128][136]

  // XCD-chunked swizzle (nwg % 8 == 0 for all launches here).
  const unsigned nwg  = gridDim.x * gridDim.y * gridDim.z;
  const unsigned flat = blockIdx.x + gridDim.x * (blockIdx.y + gridDim.y * blockIdx.z);
  const unsigned swz  = (flat & 7) * (nwg >> 3) + (flat >> 3);
  const int bx = swz % gridDim.x;
  const unsigned rem = swz / gridDim.x;
  const int by = rem % gridDim.y;
  const int z  = rem / gridDim.y;

  const __bf16* __restrict__ A  = (const __bf16*)(z == 0 ? p.a0 : z == 1 ? p.a1 : p.a2);
  const __bf16* __restrict__ BT = z == 0 ? p.b0 : z == 1 ? p.b1 : p.b2;
  CT* __restrict__ C = (CT*)(z == 0 ? p.c0 : z == 1 ? p.c1 : p.c2);

  const int tid  = threadIdx.x;
  const int wave = tid >> 6, lane = tid & 63;
  const int quad = lane >> 4, l16 = lane & 15;
  const int wr = (wave >> 1) * 64, wc = (wave & 1) * 64;
  const int m0 = by * 128, n0 = bx * 128;

  f32x4 acc[4][4] = {};

  auto issue = [&](int it, int slot) {
    const int k0 = it * 32;
    const int rr  = lane >> 2;                     // 0..15
    const int seg = (lane & 3) ^ ((rr >> 1) & 3);  // logical seg at this phys slot
    #pragma unroll
    for (int i = 0; i < 2; i++) {
      const int row = wave * 16 + i * 64 + rr;
      gl_lds16(&A [(size_t)(m0 + row) * DD + k0 + seg * 8], &Asr[slot][wave * 16 + i * 64][0]);
      gl_lds16(&BT[(size_t)(n0 + row) * DD + k0 + seg * 8], &Bsr[slot][wave * 16 + i * 64][0]);
    }
  };

  auto compute = [&](int s) {
    bf16x8 af[4], bfr[4];
    const int ph = (quad ^ ((l16 >> 1) & 3)) * 8;
    #pragma unroll
    for (int t = 0; t < 4; t++) {
      af[t]  = *(const bf16x8*)&Asr[s][wr + t * 16 + l16][ph];
      bfr[t] = *(const bf16x8*)&Bsr[s][wc + t * 16 + l16][ph];
    }
    __builtin_amdgcn_s_setprio(1);
    #pragma unroll
    for (int mt = 0; mt < 4; mt++)
      #pragma unroll
      for (int nt = 0; nt < 4; nt++)
        acc[mt][nt] = __builtin_amdgcn_mfma_f32_16x16x32_bf16(af[mt], bfr[nt], acc[mt][nt], 0, 0, 0);
    __builtin_amdgcn_s_setprio(0);
  };

  issue(0, 0); MEMFENCE();
  issue(1, 1); MEMFENCE();

  int cur = 0, pre = 2;
  #pragma unroll 1
  for (int it = 0; it < 30; it++) {
    WAITVM4();
    __builtin_amdgcn_s_barrier();
    issue(it + 2, pre);
    compute(cur);
    cur = cur == 2 ? 0 : cur + 1;
    pre = pre == 2 ? 0 : pre + 1;
  }
  WAITVM4(); __builtin_amdgcn_s_barrier(); compute(cur);
  cur = cur == 2 ? 0 : cur + 1;
  WAITVM0(); __builtin_amdgcn_s_barrier(); compute(cur);

  if constexpr (sizeof(CT) == 2) {
    if (z == vz) {
      // Transposed epilogue: C tile -> VT[col][s] (coalesced along s).
      __syncthreads();                 // all waves done reading Asr/Bsr
      #pragma unroll
      for (int mt = 0; mt < 4; mt++)
        #pragma unroll
        for (int nt = 0; nt < 4; nt++)
          #pragma unroll
          for (int r = 0; r < 4; r++)
            smT[wc + nt * 16 + l16][wr + mt * 16 + quad * 4 + r] = (__bf16)acc[mt][nt][r];
      __syncthreads();
      const int b  = m0 >> 11;          // batch of this 128-row band
      const int s0 = m0 & 2047;
      __bf16* VTp = (__bf16*)C + (size_t)b * NH * SS;
      const int sseg = (tid & 15) * 8;
      #pragma unroll
      for (int g = 0; g < 8; g++) {
        const int cl = (tid >> 4) + g * 16;
        bf16x8 vv = *(const bf16x8*)&smT[cl][sseg];
        *(bf16x8*)&VTp[(size_t)(n0 + cl) * SS + s0 + sseg] = vv;
      }
      return;
    }
  }

  // Normal epilogue: C/D layout col=lane&15, row=quad*4+r
  #pragma unroll
  for (int mt = 0; mt < 4; mt++)
    #pragma unroll
    for (int nt = 0; nt < 4; nt++)
      #pragma unroll
      for (int r = 0; r < 4; r++) {
        int row = m0 + wr + mt * 16 + quad * 4 + r;
        int col = n0 + wc + nt * 16 + l16;
        C[(size_t)row * NH + col] = (CT)acc[mt][nt][r];
      }
}

// ---------------------------------------------------------------------------
// LEGACY fallback GEMM (round-5 structure). Small-workspace paths only.
// ---------------------------------------------------------------------------
template <typename AT> struct AStage;
template <> struct AStage<float>  { f32x4 d[2][2]; };
template <> struct AStage<__bf16> { bf16x8 d[2]; };

template <typename AT, typename CT>
__global__ __launch_bounds__(256, 3) void gemm_bt(B3 p, size_t aoff) {
  __shared__ __bf16 As[128][40];
  __shared__ __bf16 Bs[4][128][32];
  const unsigned nwg  = gridDim.x * gridDim.y * gridDim.z;
  const unsigned flat = blockIdx.x + gridDim.x * (blockIdx.y + gridDim.y * blockIdx.z);
  const unsigned swz  = (flat & 7) * (nwg >> 3) + (flat >> 3);
  const int bx = swz % gridDim.x;
  const unsigned rem = swz / gridDim.x;
  const int by = rem % gridDim.y;
  const int z  = rem / gridDim.y;

  const AT* __restrict__ A = (const AT*)(z == 0 ? p.a0 : z == 1 ? p.a1 : p.a2);
  const __bf16* __restrict__ BT = z == 0 ? p.b0 : z == 1 ? p.b1 : p.b2;
  CT* __restrict__ C = (CT*)(z == 0 ? p.c0 : z == 1 ? p.c1 : p.c2);

  const int tid  = threadIdx.x;
  const int wave = tid >> 6, lane = tid & 63;
  const int quad = lane >> 4, l16 = lane & 15;
  const int wr = (wave >> 1) * 64, wc = (wave & 1) * 64;
  const int m0 = by * 128, n0 = bx * 128;

  f32x4 acc[4][4] = {};
  AStage<AT> aA, aB;

  auto loadA = [&](int k0, AStage<AT>& S) {
    #pragma unroll
    for (int i = 0; i < 2; i++) {
      int c = tid + i * 256;
      int row = c >> 2, seg = (c & 3) * 8;
      if constexpr (sizeof(AT) == 4) {
        const float* ap = (const float*)A + aoff + (size_t)(m0 + row) * DD + k0 + seg;
        S.d[i][0] = *(const f32x4*)ap;
        S.d[i][1] = *(const f32x4*)(ap + 4);
      } else {
        S.d[i] = *(const bf16x8*)((const __bf16*)A + aoff + (size_t)(m0 + row) * DD + k0 + seg);
      }
    }
  };
  auto issueB = [&](int k0, int buf) {
    #pragma unroll
    for (int i = 0; i < 2; i++) {
      int rr  = lane >> 2;
      int row = wave * 16 + i * 64 + rr;
      int seg = (lane & 3) ^ ((rr >> 1) & 3);
      gl_lds16(&BT[(size_t)(n0 + row) * DD + k0 + seg * 8],
               &Bs[buf][wave * 16 + i * 64][0]);
    }
  };

  auto step = [&](int it, AStage<AT>& S, bool last, bool tail) {
    if (last) { WAITVM0(); }
    else if constexpr (sizeof(AT) == 4) { WAITVM6(); }
    else { WAITVM4(); }
    __builtin_amdgcn_s_barrier();
    #pragma unroll
    for (int i = 0; i < 2; i++) {
      int c = tid + i * 256;
      bf16x8 av;
      if constexpr (sizeof(AT) == 4) {
        #pragma unroll
        for (int j = 0; j < 4; j++) {
          av[j]     = (__bf16)S.d[i][0][j];
          av[j + 4] = (__bf16)S.d[i][1][j];
        }
      } else {
        av = S.d[i];
      }
      *(bf16x8*)&As[c >> 2][(c & 3) * 8] = av;
    }
    WAITLGKM0();
    __builtin_amdgcn_s_barrier();
    if (!tail) {
      issueB((it + 2) * 32, (it + 2) & 3);
      loadA((it + 2) * 32, S);
    }
    const int buf = it & 3;
    bf16x8 af[4], bfr[4];
    #pragma unroll
    for (int t = 0; t < 4; t++) {
      af[t]  = *(const bf16x8*)&As[wr + t * 16 + l16][quad * 8];
      bfr[t] = *(const bf16x8*)&Bs[buf][wc + t * 16 + l16][(quad ^ ((l16 >> 1) & 3)) * 8];
    }
    __builtin_amdgcn_s_setprio(1);
    #pragma unroll
    for (int mt = 0; mt < 4; mt++)
      #pragma unroll
      for (int nt = 0; nt < 4; nt++)
        acc[mt][nt] = __builtin_amdgcn_mfma_f32_16x16x32_bf16(af[mt], bfr[nt], acc[mt][nt], 0, 0, 0);
    __builtin_amdgcn_s_setprio(0);
  };

  issueB(0, 0);  loadA(0, aA);
  MEMFENCE();
  issueB(32, 1); loadA(32, aB);
  MEMFENCE();

  for (int it2 = 0; it2 < 15; it2++) {
    step(2 * it2,     aA, false, false);
    step(2 * it2 + 1, aB, false, false);
  }
  step(30, aA, false, true);
  step(31, aB, true,  true);

  #pragma unroll
  for (int mt = 0; mt < 4; mt++)
    #pragma unroll
    for (int nt = 0; nt < 4; nt++)
      #pragma unroll
      for (int r = 0; r < 4; r++) {
        int row = m0 + wr + mt * 16 + quad * 4 + r;
        int col = n0 + wc + nt * 16 + l16;
        C[(size_t)row * NH + col] = (CT)acc[mt][nt][r];
      }
}

// ---------------------------------------------------------------------------
// Causal flash attention, ROUND 9: BQ=64 paired-triangle geometry (round 8)
// + packed-LDS P transpose.
//
// Round-8 counters: VALUBusy 40.8% vs MfmaUtil 17.1% — VALU-bound, and the
// register P-transpose (8 cvt_pk + 32 quad-dependent cndmask + 12
// ds_bpermute per k-tile) is ~half the VALU issue, serial between softmax
// and PV. Replaced with a Ps LDS round-trip: pack 4 p-values -> one
// ds_write_b64 per nt-block (4 writes/tile), PV reads A-frags with 2
// ds_read_b128. Rows wave-private (lane l16 = q-col = row wave*16+l16):
// same-wave RAW, no barrier. Stride 72 -> conflict-free b128 reads
// ((row+quad)%8 covers all slots); b64 writes ~4-way on 4 ops (negligible).
// Regime note: round 2 found the REVERSE swap neutral — but that baseline
// was latency-bound (all pipes <20%); this one is VALU-bound (41%).
// ---------------------------------------------------------------------------
__global__ __launch_bounds__(256, 4) void attn_k(
    const __bf16* __restrict__ Q, const __bf16* __restrict__ K,
    const __bf16* __restrict__ VT, __bf16* __restrict__ O) {
  __shared__ __bf16 Ks[64][68];   // [kpos][dh]
  __shared__ __bf16 Vs[64][68];   // [dh][kpos]
  __shared__ __bf16 Ps[64][72];   // [qrow][kpos], padded for b128 reads

  const int tid  = threadIdx.x;
  const int wave = tid >> 6, lane = tid & 63;
  const int quad = lane >> 4, l16 = lane & 15;

  // XCD-grouped decode: 16 consecutive slots on one XCD form one (h,z).
  const int n    = blockIdx.x;
  const int xcd  = n & 7, slot = n >> 3;
  const int gidx = xcd + 8 * (slot >> 4);   // (h,z) group id
  const int bx   = slot & 15;               // pair index 0..15
  const int h = gidx & 15, z = gidx >> 4;

  const __bf16* Qg = Q + (size_t)z * SS * NH + h * DHE;      // [s][dh] stride NH
  const __bf16* Kg = K + (size_t)z * SS * NH + h * DHE;
  const __bf16* Vg = VT + ((size_t)z * HH + h) * DHE * SS;   // [dh][s]
  __bf16*       Og = O + (size_t)z * SS * NH + h * DHE;

  const int prow_i = wave * 16 + l16;        // this lane's q row in Ps

  bf16x8 kreg[2], vreg[2];
  auto loadKV = [&](int k0) {
    #pragma unroll
    for (int i = 0; i < 2; i++) {
      int v = tid + i * 256;   // 0..511 chunks of 8 elems = 64x64 tile
      kreg[i] = *(const bf16x8*)&Kg[(size_t)(k0 + (v >> 3)) * NH + (v & 7) * 8];
      vreg[i] = *(const bf16x8*)&Vg[(size_t)(v >> 3) * SS + k0 + (v & 7) * 8];
    }
  };

  #pragma unroll 1
  for (int seg = 0; seg < 2; seg++) {
    const int qt = seg ? bx : 31 - bx;       // {16..31} then {0..15}
    const int q0 = qt * 64;
    const int ntiles = qt + 1;

    // Q frag raw (K carries the softmax scale). Lane l16 = q-col.
    const int qrow = q0 + wave * 16 + l16;
    bf16x8 qf[2];
    #pragma unroll
    for (int kk = 0; kk < 2; kk++)
      qf[kk] = *(const bf16x8*)&Qg[(size_t)qrow * NH + kk * 32 + quad * 8];

    loadKV(0);
    float prows = 0.f;
    f32x4 oacc[4] = {};

    for (int kt = 0; kt < ntiles; kt++) {
      const int k0 = kt * 64;
      __syncthreads();
      #pragma unroll
      for (int i = 0; i < 2; i++) {
        int v = tid + i * 256;
        *(bf16x8*)&Ks[v >> 3][(v & 7) * 8] = kreg[i];
        *(bf16x8*)&Vs[v >> 3][(v & 7) * 8] = vreg[i];
      }
      __syncthreads();
      if (kt + 1 < ntiles) loadKV(k0 + 64);

      const bool diag = (kt == ntiles - 1);
      const int nq  = diag ? wave + 1 : 4;          // QK blocks with live data
      const int nsm = diag ? ((wave + 2) & ~1) : 4; // processed blocks (even)
      const int nkk = nsm >> 1;                     // PV 32-wide k-chunks

      // S^T = K_scaled Q^T : sc[nt] holds kpos rows nt*16+quad*4+r, q col l16
      f32x4 sc[4] = {};
      __builtin_amdgcn_s_setprio(1);
      #pragma unroll
      for (int kk = 0; kk < 2; kk++)
        #pragma unroll
        for (int nt = 0; nt < 4; nt++)
          if (nt < nq) {
            bf16x8 kf = *(const bf16x8*)&Ks[nt * 16 + l16][kk * 32 + quad * 8];
            sc[nt] = __builtin_amdgcn_mfma_f32_16x16x32_bf16(kf, qf[kk], sc[nt], 0, 0, 0);
          }
      __builtin_amdgcn_s_setprio(0);

      // Register softmax (p = exp2(s)); packed bf16 pairs written through
      // Ps (LDS) to effect the 4-lane transpose for PV's A-fragment.
      // Lane (quad,l16): kpos = nt*16 + quad*4 + r, q-row = prow_i -> one
      // contiguous 4-elem (8B) write per nt. Wave-private rows, no barrier.
      #pragma unroll
      for (int nt = 0; nt < 4; nt++)
        if (nt < nsm) {
          float p0, p1, p2, p3;
          {
            float v0 = sc[nt][0], v1 = sc[nt][1], v2 = sc[nt][2], v3 = sc[nt][3];
            if (diag) {
              const int kb = k0 + nt * 16 + quad * 4;
              if (kb + 0 > qrow) v0 = NEG_BIG;
              if (kb + 1 > qrow) v1 = NEG_BIG;
              if (kb + 2 > qrow) v2 = NEG_BIG;
              if (kb + 3 > qrow) v3 = NEG_BIG;
            }
            p0 = __builtin_amdgcn_exp2f(v0);
            p1 = __builtin_amdgcn_exp2f(v1);
            p2 = __builtin_amdgcn_exp2f(v2);
            p3 = __builtin_amdgcn_exp2f(v3);
            prows += (p0 + p1) + (p2 + p3);
          }
          uint2 w;
          w.x = pack_bf2(p0, p1);
          w.y = pack_bf2(p2, p3);
          *(uint2*)&Ps[prow_i][nt * 16 + quad * 4] = w;   // ds_write_b64
        }

      // O += P V  (A-frag from Ps: lane l16 = q-row, quad*8 = k-chunk;
      // same-wave RAW with the writes above, ordered by lgkmcnt)
      __builtin_amdgcn_s_setprio(1);
      #pragma unroll
      for (int kk = 0; kk < 2; kk++)
        if (kk < nkk) {
          bf16x8 a = *(const bf16x8*)&Ps[prow_i][kk * 32 + quad * 8];
          #pragma unroll
          for (int dt = 0; dt < 4; dt++) {
            bf16x8 vf = *(const bf16x8*)&Vs[dt * 16 + l16][kk * 32 + quad * 8];
            oacc[dt] = __builtin_amdgcn_mfma_f32_16x16x32_bf16(a, vf, oacc[dt], 0, 0, 0);
          }
        }
      __builtin_amdgcn_s_setprio(0);
    }

    prows += __shfl_xor(prows, 16, 64);
    prows += __shfl_xor(prows, 32, 64);

    #pragma unroll
    for (int r = 0; r < 4; r++) {
      float tot = __shfl(prows, quad * 4 + r, 64);
      float inv = tot > 0.f ? 1.0f / tot : 0.f;
      int qg = q0 + wave * 16 + quad * 4 + r;
      #pragma unroll
      for (int dt = 0; dt < 4; dt++)
        Og[(size_t)qg * NH + dt * 16 + l16] = (__bf16)(oacc[dt][r] * inv);
    }
  }
}

// ---------------------------------------------------------------------------
extern "C" void kernel_launch(void* const* d_in, const int* in_sizes, int n_in,
                              void* d_out, int out_size, void* d_ws, size_t ws_size,
                              hipStream_t stream) {
  const float* x_q = (const float*)d_in[0];
  const float* x_k = (const float*)d_in[1];
  const float* x_v = (const float*)d_in[2];
  // d_in[3] = causal mask — statically known, unused
  const float* Wq = (const float*)d_in[4];
  const float* Wk = (const float*)d_in[5];
  const float* Wv = (const float*)d_in[6];
  const float* Wo = (const float*)d_in[7];
  float* out = (float*)d_out;

  const size_t WTE = (size_t)DD * NH;           // 1M elems per weight
  const size_t PB  = (size_t)SS * NH;           // per-batch elems (2M)
  const size_t FULLB = (size_t)BB * PB;         // 8M elems

  char* ws = (char*)d_ws;
  __bf16* WqT = (__bf16*)ws;
  __bf16* WkT = WqT + WTE;
  __bf16* WvT = WkT + WTE;
  __bf16* WoT = WvT + WTE;
  __bf16* buf0 = WoT + WTE;                     // after 8 MB of weights

  wtrans_k<<<dim3(32, 32, 4), 256, 0, stream>>>(Wq, Wk, Wv, Wo, WqT, WkT, WvT, WoT);

  const size_t needFast = 4 * WTE * 2 + 4 * FULLB * 2 + 3 * FULLB * 2;  // 120 MB
  const size_t needFull = 4 * WTE * 2 + 4 * FULLB * 2;                  // 72 MB
  if (ws_size >= needFast) {
    __bf16* Qb  = buf0;
    __bf16* Kb  = Qb + FULLB;
    __bf16* Vb  = Kb + FULLB;         // Ob lives here (V goes straight to VT)
    __bf16* VT  = Vb + FULLB;
    __bf16* xqb = VT + FULLB;
    __bf16* xkb = xqb + FULLB;
    __bf16* xvb = xkb + FULLB;
    __bf16* Ob  = Vb;
    cvt_k<<<dim3(1024, 1, 3), 256, 0, stream>>>(x_q, x_k, x_v, xqb, xkb, xvb);
    B3 qkv = { xqb, xkb, xvb, WqT, WkT, WvT, Qb, Kb, VT };
    gemm_bb<__bf16><<<dim3(8, 64, 3), 256, 0, stream>>>(qkv, 2);   // z==2 -> VT
    attn_k<<<dim3((SS / 128) * HH * BB), 256, 0, stream>>>(Qb, Kb, VT, Ob);
    B3 og = { Ob, Ob, Ob, WoT, WoT, WoT, out, out, out };
    gemm_bb<float><<<dim3(8, 64, 1), 256, 0, stream>>>(og, -1);
  } else if (ws_size >= needFull) {
    __bf16* Qb = buf0;
    __bf16* Kb = Qb + FULLB;
    __bf16* Vb = Kb + FULLB;
    __bf16* VT = Vb + FULLB;
    __bf16* Ob = Vb;                  // alias
    B3 qkv = { x_q, x_k, x_v, WqT, WkT, WvT, Qb, Kb, Vb };
    gemm_bt<float, __bf16><<<dim3(8, 64, 3), 256, 0, stream>>>(qkv, 0);
    vtrans_k<<<dim3(SS / 32, NH / 32, BB), 256, 0, stream>>>(Vb, VT);
    attn_k<<<dim3((SS / 128) * HH * BB), 256, 0, stream>>>(Qb, Kb, VT, Ob);
    B3 og = { Ob, Ob, Ob, WoT, WoT, WoT, out, out, out };
    gemm_bt<__bf16, float><<<dim3(8, 64, 1), 256, 0, stream>>>(og, 0);
  } else {
    __bf16* Qb = buf0;
    __bf16* Kb = Qb + PB;
    __bf16* Vb = Kb + PB;
    __bf16* VT = Vb + PB;
    __bf16* Ob = Vb;                  // alias
    for (int b = 0; b < BB; b++) {
      const size_t boff = (size_t)b * PB;
      B3 qkv = { x_q, x_k, x_v, WqT, WkT, WvT, Qb, Kb, Vb };
      gemm_bt<float, __bf16><<<dim3(8, 16, 3), 256, 0, stream>>>(qkv, boff);
      vtrans_k<<<dim3(SS / 32, NH / 32, 1), 256, 0, stream>>>(Vb, VT);
      attn_k<<<dim3((SS / 128) * HH), 256, 0, stream>>>(Qb, Kb, VT, Ob);
      B3 og = { Ob, Ob, Ob, WoT, WoT, WoT, out + boff, out + boff, out + boff };
      gemm_bt<__bf16, float><<<dim3(8, 16, 1), 256, 0, stream>>>(og, 0);
    }
  }
}